// Round 16
// baseline (69.781 us; speedup 1.0000x reference)
//
#include <hip/hip_runtime.h>
#include <hip/hip_bf16.h>
#include <stdint.h>

typedef __attribute__((ext_vector_type(8))) short bf16x8;
typedef __attribute__((ext_vector_type(16))) float f32x16;
using bf16 = __hip_bfloat16;

static constexpr int Mdim = 512;   // A batch
static constexpr int Ndim = 64;    // B batch
static constexpr int Cdim = 128;   // channels (K of the GEMM)
static constexpr int Pdim = 64;    // H*W positions
static constexpr float EPS_ADD = 0.001f;

#define SB0 __builtin_amdgcn_sched_barrier(0)
#define WAITV(N) asm volatile("s_waitcnt vmcnt(" #N ")" ::: "memory")

// ---------------------------------------------------------------------------
// async global->LDS, 16B per lane
// ---------------------------------------------------------------------------
__device__ __forceinline__ void gll16(const void* gsrc, void* ldst) {
    const __attribute__((address_space(1))) unsigned int* g =
        (const __attribute__((address_space(1))) unsigned int*)gsrc;
    __attribute__((address_space(3))) unsigned int* l =
        (__attribute__((address_space(3))) unsigned int*)(uintptr_t)ldst;
    __builtin_amdgcn_global_load_lds(g, l, 16, 0, 0);
}

// ---------------------------------------------------------------------------
// prep (fused, UNCHANGED — verified): fragment-ordered outputs.
//   A-tile (per m): idx = h*4096 + ks*512 + lane*8 + e
//     p = h*32 + (lane&31), c = ks*16 + (lane>>5)*8 + e
//   G-tile (per n): idx = qt*4096 + ks*512 + lane*8 + e
//     q = qt*32 + (lane&31), c = ks*16 + (lane>>5)*8 + e
// ---------------------------------------------------------------------------
__global__ void prep_kernel(const float* __restrict__ A, const float* __restrict__ B,
                            const float* __restrict__ Wg,
                            bf16* __restrict__ Afrag, bf16* __restrict__ Gfrag) {
    __shared__ float lds[128 * 65];
    const int t = threadIdx.x;

    if (blockIdx.x < 512) {
        const int m = blockIdx.x;
        const float* __restrict__ Am = A + (size_t)m * (Cdim * Pdim);
#pragma unroll
        for (int i = 0; i < 8; ++i) {
            int v = t + i * 256;
            int gidx = v * 4;
            int c = gidx >> 6, p = gidx & 63;
            float4 val = *reinterpret_cast<const float4*>(Am + gidx);
            float* dst = &lds[c * 65 + p];
            dst[0] = val.x; dst[1] = val.y; dst[2] = val.z; dst[3] = val.w;
        }
        __syncthreads();

        unsigned* __restrict__ dst32 = (unsigned*)(Afrag + (size_t)m * 8192);
#pragma unroll
        for (int i = 0; i < 16; ++i) {
            int pr = t + i * 256;
            int p = pr >> 6;
            int c = (pr & 63) << 1;
            float f0 = lds[c * 65 + p];
            float f1 = lds[(c + 1) * 65 + p];
            union { bf16 hh[2]; unsigned u; } pk;
            pk.hh[0] = __float2bfloat16(f0);
            pk.hh[1] = __float2bfloat16(f1);
            int h = p >> 5, l31 = p & 31;
            int ks = c >> 4, hi = (c >> 3) & 1, e = c & 7;
            dst32[h * 2048 + ks * 256 + hi * 128 + l31 * 4 + (e >> 1)] = pk.u;
        }
    } else {
        const int nb = blockIdx.x - 512;
        const int n  = nb >> 2;
        const int q0 = (nb & 3) * 16;
        const float* __restrict__ Bn = B + (size_t)n * (Cdim * Pdim);
#pragma unroll
        for (int i = 0; i < 8; ++i) {
            int v = t + i * 256;
            int gidx = v * 4;
            int c = gidx >> 6, q = gidx & 63;
            float4 val = *reinterpret_cast<const float4*>(Bn + gidx);
            float* dst = &lds[c * 65 + q];
            dst[0] = val.x; dst[1] = val.y; dst[2] = val.z; dst[3] = val.w;
        }
        __syncthreads();

        const int d  = t & 127;
        const int qb = q0 + (t >> 7) * 8;
        float acc[8] = {0.f, 0.f, 0.f, 0.f, 0.f, 0.f, 0.f, 0.f};
        for (int c = 0; c < 128; ++c) {
            float w = Wg[c * 128 + d];
#pragma unroll
            for (int qi = 0; qi < 8; ++qi)
                acc[qi] = fmaf(lds[c * 65 + qb + qi], w, acc[qi]);
        }
        bf16* __restrict__ gdst = Gfrag + (size_t)n * 8192;
        const int ks = d >> 4, hi = (d >> 3) & 1, e = d & 7;
#pragma unroll
        for (int qi = 0; qi < 8; ++qi) {
            int q = qb + qi;
            int qt = q >> 5, l31 = q & 31;
            gdst[qt * 4096 + ks * 512 + hi * 256 + l31 * 8 + e] = __float2bfloat16(acc[qi]);
        }
    }
}

// ---------------------------------------------------------------------------
// gemm_max v13: R=4 — wave = 4 m's x one p-half; a[4][8] = 128 VGPR resident.
//  - One 16KB G LDS-read feeds 64 MFMA -> 256 B/MFMA (half of v10/v12's 512).
//  - 4 independent 8-deep acc chains per qt (latency-friendly); online max
//    over qt reuses the 4 accs.
//  - G: 3 rolling 16KB bufs (48KB LDS), dist-2 prefetch; block = 4 waves
//    (mi,h) = 8 m's; 8 n-steps; grid 512 = 2 blocks/CU (2 barrier domains).
//  - UNIFORM vmcnt ledger (fixes v11/v12's non-store-lane under-drain):
//    ALL lanes store 2 floats/step (lane (hi,l31) stores m-subs hi*2,hi*2+1;
//    value is lane-replicated after the shfl fold). Body order:
//    [compute(s), stores(s), stage(s+2)] -> entry-of-step queue:
//    stage(s), stores(s-1)(2), stage(s+1)(4) -> WAITV(6) drains stage(s).
//    step0: WAITV(4) (A(32)+stage0 drained, leave stage1); step7: WAITV(2).
//  - Safety: stage(s+2) writes buf (s-1)%3; issued after the entry barrier
//    of step s, which proves all waves' compute(s-1) reads retired.
// bid = bn*64+mg: same-A blocks (fixed mg, bn=0..7) all = mg (mod 8) -> one
// XCD's L2. MFMA 32x32x16, mfma(G,A): D col = lane&31 = p, row = q (m74/m101).
// ---------------------------------------------------------------------------
__global__ __launch_bounds__(256, 2)
void gemm_max_kernel(const bf16* __restrict__ Afrag, const bf16* __restrict__ Gfrag,
                     float* __restrict__ out) {
    __shared__ bf16 sG[3][8192];          // 3 x 16KB rolling, fragment order
    const int tid  = threadIdx.x;
    const int lane = tid & 63;
    const int wv   = tid >> 6;            // 0..3
    const int mi = wv >> 1, h = wv & 1;   // wave: m-quad index, p-half
    const int l31 = lane & 31, hi = lane >> 5;
    const int mg = blockIdx.x & 63;       // 64 m-groups of 8
    const int bn = blockIdx.x >> 6;       // 8 n-groups of 8
    const int m0 = mg * 8 + mi * 4;       // wave handles m0..m0+3

    // ---- A resident: 32 coalesced 1KB loads (oldest vmcnt events) ----
    bf16x8 a[4][8];                       // [m-sub][ks]
#pragma unroll
    for (int u = 0; u < 4; ++u) {
        const bf16* Ap = Afrag + (size_t)(m0 + u) * 8192 + h * 4096 + lane * 8;
#pragma unroll
        for (int ks = 0; ks < 8; ++ks)
            a[u][ks] = *reinterpret_cast<const bf16x8*>(Ap + ks * 512);
    }
    asm volatile("" ::: "memory");        // pin A-loads before stage issues

    const char* Gsrc = (const char*)(Gfrag + (size_t)(bn * 8) * 8192);
    auto stageG = [&](int s) {            // 16KB: 4 x gll16 per thread
        char* dst = (char*)&sG[s % 3][0];
        const char* src = Gsrc + (size_t)s * 16384;
#pragma unroll
        for (int i = 0; i < 4; ++i) {
            int f = (i * 256 + tid) * 16;
            gll16(src + f, dst + f);
        }
    };
    stageG(0);
    stageG(1);

    const f32x16 z16 = {0.f,0.f,0.f,0.f,0.f,0.f,0.f,0.f,0.f,0.f,0.f,0.f,0.f,0.f,0.f,0.f};

    auto step = [&](int s) {
        const char* gb = (const char*)&sG[s % 3][0] + lane * 16;
        float r0, r1, r2, r3;
#pragma unroll
        for (int qt = 0; qt < 2; ++qt) {
            f32x16 acc0, acc1, acc2, acc3;   // reused across qt (online max)
            __builtin_amdgcn_s_setprio(1);
#pragma unroll
            for (int ks = 0; ks < 8; ++ks) {
                bf16x8 gf = *reinterpret_cast<const bf16x8*>(gb + qt * 8192 + ks * 1024);
                acc0 = __builtin_amdgcn_mfma_f32_32x32x16_bf16(gf, a[0][ks], ks == 0 ? z16 : acc0, 0, 0, 0);
                acc1 = __builtin_amdgcn_mfma_f32_32x32x16_bf16(gf, a[1][ks], ks == 0 ? z16 : acc1, 0, 0, 0);
                acc2 = __builtin_amdgcn_mfma_f32_32x32x16_bf16(gf, a[2][ks], ks == 0 ? z16 : acc2, 0, 0, 0);
                acc3 = __builtin_amdgcn_mfma_f32_32x32x16_bf16(gf, a[3][ks], ks == 0 ? z16 : acc3, 0, 0, 0);
            }
            __builtin_amdgcn_s_setprio(0);
            float t0 = fmaxf(acc0[0], acc0[1]);
            float t1 = fmaxf(acc1[0], acc1[1]);
            float t2 = fmaxf(acc2[0], acc2[1]);
            float t3 = fmaxf(acc3[0], acc3[1]);
#pragma unroll
            for (int j = 2; j < 16; ++j) {
                t0 = fmaxf(t0, acc0[j]); t1 = fmaxf(t1, acc1[j]);
                t2 = fmaxf(t2, acc2[j]); t3 = fmaxf(t3, acc3[j]);
            }
            if (qt == 0) { r0 = t0; r1 = t1; r2 = t2; r3 = t3; }
            else { r0 = fmaxf(r0, t0); r1 = fmaxf(r1, t1);
                   r2 = fmaxf(r2, t2); r3 = fmaxf(r3, t3); }
        }
        // fold q hi-halves (value becomes lane-replicated across hi)
        r0 = fmaxf(r0, __shfl_xor(r0, 32));
        r1 = fmaxf(r1, __shfl_xor(r1, 32));
        r2 = fmaxf(r2, __shfl_xor(r2, 32));
        r3 = fmaxf(r3, __shfl_xor(r3, 32));
        // ALL lanes store 2: lane (hi,l31) stores m-subs hi*2, hi*2+1
        const int n = bn * 8 + s;
        const float sa = hi ? r2 : r0;        // cndmask, static indices
        const float sb = hi ? r3 : r1;
        float* ob = out + (size_t)(m0 + hi * 2) * 4096 + n * 64 + h * 32 + l31;
        ob[0]    = fmaxf(sa, 0.f) + EPS_ADD;
        ob[4096] = fmaxf(sb, 0.f) + EPS_ADD;  // next m-sub, same (n,p)
    };

    // ---- step 0: drain A + stage0 (leave stage1) ----
    WAITV(4); __builtin_amdgcn_s_barrier(); SB0;
    step(0); SB0; stageG(2); SB0;

    // ---- steps 1..5: steady WAITV(6) ----
    for (int s = 1; s <= 5; ++s) {
        WAITV(6); __builtin_amdgcn_s_barrier(); SB0;
        step(s); SB0; stageG(s + 2); SB0;
    }

    // ---- step 6 (no stage issued) ----
    WAITV(6); __builtin_amdgcn_s_barrier(); SB0;
    step(6); SB0;

    // ---- step 7 ----
    WAITV(2); __builtin_amdgcn_s_barrier(); SB0;
    step(7);
}

// ---------------------------------------------------------------------------
extern "C" void kernel_launch(void* const* d_in, const int* in_sizes, int n_in,
                              void* d_out, int out_size, void* d_ws, size_t ws_size,
                              hipStream_t stream) {
    const float* A  = (const float*)d_in[0];
    const float* B  = (const float*)d_in[1];
    const float* Wg = (const float*)d_in[2];
    float* out = (float*)d_out;

    bf16* Afrag = (bf16*)d_ws;                                      // 512 x 8192 bf16 = 8 MiB
    bf16* Gfrag = (bf16*)((char*)d_ws + (size_t)Mdim * Pdim * Cdim * sizeof(bf16)); // 64 x 8192 bf16

    prep_kernel<<<768, 256, 0, stream>>>(A, B, Wg, Afrag, Gfrag);
    gemm_max_kernel<<<512, 256, 0, stream>>>(Afrag, Gfrag, out);   // 8 bn x 64 mg
}

// Round 17
// 48.514 us; speedup vs baseline: 1.4384x; 1.4384x over previous
//
#include <hip/hip_runtime.h>
#include <hip/hip_bf16.h>
#include <stdint.h>

typedef __attribute__((ext_vector_type(8))) short bf16x8;
typedef __attribute__((ext_vector_type(16))) float f32x16;
using bf16 = __hip_bfloat16;

static constexpr int Mdim = 512;   // A batch
static constexpr int Ndim = 64;    // B batch
static constexpr int Cdim = 128;   // channels (K of the GEMM)
static constexpr int Pdim = 64;    // H*W positions
static constexpr float EPS_ADD = 0.001f;

#define SB0 __builtin_amdgcn_sched_barrier(0)
#define WAITV(N) asm volatile("s_waitcnt vmcnt(" #N ")" ::: "memory")

// ---------------------------------------------------------------------------
// async global->LDS, 16B per lane
// ---------------------------------------------------------------------------
__device__ __forceinline__ void gll16(const void* gsrc, void* ldst) {
    const __attribute__((address_space(1))) unsigned int* g =
        (const __attribute__((address_space(1))) unsigned int*)gsrc;
    __attribute__((address_space(3))) unsigned int* l =
        (__attribute__((address_space(3))) unsigned int*)(uintptr_t)ldst;
    __builtin_amdgcn_global_load_lds(g, l, 16, 0, 0);
}

// ---------------------------------------------------------------------------
// prep (fused, UNCHANGED — verified): fragment-ordered outputs.
//   A-tile (per m): idx = h*4096 + ks*512 + lane*8 + e
//     p = h*32 + (lane&31), c = ks*16 + (lane>>5)*8 + e
//   G-tile (per n): idx = qt*4096 + ks*512 + lane*8 + e
//     q = qt*32 + (lane&31), c = ks*16 + (lane>>5)*8 + e
// ---------------------------------------------------------------------------
__global__ void prep_kernel(const float* __restrict__ A, const float* __restrict__ B,
                            const float* __restrict__ Wg,
                            bf16* __restrict__ Afrag, bf16* __restrict__ Gfrag) {
    __shared__ float lds[128 * 65];
    const int t = threadIdx.x;

    if (blockIdx.x < 512) {
        const int m = blockIdx.x;
        const float* __restrict__ Am = A + (size_t)m * (Cdim * Pdim);
#pragma unroll
        for (int i = 0; i < 8; ++i) {
            int v = t + i * 256;
            int gidx = v * 4;
            int c = gidx >> 6, p = gidx & 63;
            float4 val = *reinterpret_cast<const float4*>(Am + gidx);
            float* dst = &lds[c * 65 + p];
            dst[0] = val.x; dst[1] = val.y; dst[2] = val.z; dst[3] = val.w;
        }
        __syncthreads();

        unsigned* __restrict__ dst32 = (unsigned*)(Afrag + (size_t)m * 8192);
#pragma unroll
        for (int i = 0; i < 16; ++i) {
            int pr = t + i * 256;
            int p = pr >> 6;
            int c = (pr & 63) << 1;
            float f0 = lds[c * 65 + p];
            float f1 = lds[(c + 1) * 65 + p];
            union { bf16 hh[2]; unsigned u; } pk;
            pk.hh[0] = __float2bfloat16(f0);
            pk.hh[1] = __float2bfloat16(f1);
            int h = p >> 5, l31 = p & 31;
            int ks = c >> 4, hi = (c >> 3) & 1, e = c & 7;
            dst32[h * 2048 + ks * 256 + hi * 128 + l31 * 4 + (e >> 1)] = pk.u;
        }
    } else {
        const int nb = blockIdx.x - 512;
        const int n  = nb >> 2;
        const int q0 = (nb & 3) * 16;
        const float* __restrict__ Bn = B + (size_t)n * (Cdim * Pdim);
#pragma unroll
        for (int i = 0; i < 8; ++i) {
            int v = t + i * 256;
            int gidx = v * 4;
            int c = gidx >> 6, q = gidx & 63;
            float4 val = *reinterpret_cast<const float4*>(Bn + gidx);
            float* dst = &lds[c * 65 + q];
            dst[0] = val.x; dst[1] = val.y; dst[2] = val.z; dst[3] = val.w;
        }
        __syncthreads();

        const int d  = t & 127;
        const int qb = q0 + (t >> 7) * 8;
        float acc[8] = {0.f, 0.f, 0.f, 0.f, 0.f, 0.f, 0.f, 0.f};
        for (int c = 0; c < 128; ++c) {
            float w = Wg[c * 128 + d];
#pragma unroll
            for (int qi = 0; qi < 8; ++qi)
                acc[qi] = fmaf(lds[c * 65 + qb + qi], w, acc[qi]);
        }
        bf16* __restrict__ gdst = Gfrag + (size_t)n * 8192;
        const int ks = d >> 4, hi = (d >> 3) & 1, e = d & 7;
#pragma unroll
        for (int qi = 0; qi < 8; ++qi) {
            int q = qb + qi;
            int qt = q >> 5, l31 = q & 31;
            gdst[qt * 4096 + ks * 512 + hi * 256 + l31 * 8 + e] = __float2bfloat16(acc[qi]);
        }
    }
}

// ---------------------------------------------------------------------------
// gemm_max v15: v12 config + m201-style fine phase interleave inside each
// n-step. Wave = 2 m's x one p-half; a[2][8] = 32 VGPR resident.
// Per step (one n), TWO qt-phases, each:
//   {8 ds_read_b128 -> gf[8]; 2 gll16 (half of stage(s+2)); s_barrier;
//    lgkmcnt(0)+SB0; setprio(1); 16 MFMA (2 chains); setprio(0); reduce}
// Ph1's ds_reads sit after ph0's MFMA with no barrier between -> LDS pipe
// overlaps MFMA pipe; pre-MFMA barrier+lgkm aligns all 4 waves' MFMA
// clusters (T3 shape); setprio arbitrates (T5 regime).
// Mid-step barriers are pure alignment (same buffer, no new hazards);
// vmcnt ledger IDENTICAL to v12's proven one (4 gll16 then 2 store-instr
// per wave per step): step0 W(4); step1 W(6); steps2..6 W(8); step7 W(4).
// Buffer safety: stage(s+2) writes buf (s-1)%3 whose readers all passed the
// step-s entry barrier. Grid 1024 = 8 bn x 128 mg, (256,3), 48KB LDS.
// MFMA 32x32x16, mfma(G,A): D col = lane&31 = p, row = q (m74/m101).
// ---------------------------------------------------------------------------
__global__ __launch_bounds__(256, 3)
void gemm_max_kernel(const bf16* __restrict__ Afrag, const bf16* __restrict__ Gfrag,
                     float* __restrict__ out) {
    __shared__ bf16 sG[3][8192];          // 3 x 16KB rolling, fragment order
    const int tid  = threadIdx.x;
    const int lane = tid & 63;
    const int wv   = tid >> 6;            // 0..3
    const int mi = wv >> 1, h = wv & 1;   // wave: m-pair index, p-half
    const int l31 = lane & 31, hi = lane >> 5;
    const int mg = blockIdx.x & 127;      // 128 m-groups of 4
    const int bn = blockIdx.x >> 7;       // 8 n-groups of 8
    const int m0 = mg * 4 + mi * 2;       // wave handles m0, m0+1

    // ---- A resident: 16 coalesced 1KB loads (oldest vmcnt events) ----
    bf16x8 a[2][8];                       // [m-sub][ks]
#pragma unroll
    for (int u = 0; u < 2; ++u) {
        const bf16* Ap = Afrag + (size_t)(m0 + u) * 8192 + h * 4096 + lane * 8;
#pragma unroll
        for (int ks = 0; ks < 8; ++ks)
            a[u][ks] = *reinterpret_cast<const bf16x8*>(Ap + ks * 512);
    }
    asm volatile("" ::: "memory");        // pin A-loads before stage issues

    const char* Gsrc = (const char*)(Gfrag + (size_t)(bn * 8) * 8192);
    auto stageFull = [&](int s) {         // prologue only: all 4 gll16
        char* dst = (char*)&sG[s % 3][0];
        const char* src = Gsrc + (size_t)s * 16384;
#pragma unroll
        for (int i = 0; i < 4; ++i) {
            int f = (i * 256 + tid) * 16;
            gll16(src + f, dst + f);
        }
    };
    stageFull(0);
    stageFull(1);

    const f32x16 z16 = {0.f,0.f,0.f,0.f,0.f,0.f,0.f,0.f,0.f,0.f,0.f,0.f,0.f,0.f,0.f,0.f};

    // step s: two m201-shaped phases; ss = stage target (-1 = none)
    auto step = [&](int s, int ss) {
        const char* gb = (const char*)&sG[s % 3][0] + lane * 16;
        char* sdst = (char*)&sG[((ss >= 0 ? ss : 0)) % 3][0];
        const char* ssrc = Gsrc + (size_t)(ss >= 0 ? ss : 0) * 16384;
        float r0, r1;
#pragma unroll
        for (int qt = 0; qt < 2; ++qt) {
            // ---- phase qt: ds-load cluster + half-stage ----
            bf16x8 gf[8];
#pragma unroll
            for (int ks = 0; ks < 8; ++ks)
                gf[ks] = *reinterpret_cast<const bf16x8*>(gb + qt * 8192 + ks * 1024);
            if (ss >= 0) {
#pragma unroll
                for (int i = 0; i < 2; ++i) {
                    int f = ((qt * 2 + i) * 256 + tid) * 16;
                    gll16(ssrc + f, sdst + f);
                }
            }
            __builtin_amdgcn_s_barrier();                       // align waves
            asm volatile("s_waitcnt lgkmcnt(0)" ::: "memory");  // reads done
            SB0;
            __builtin_amdgcn_s_setprio(1);
            f32x16 acc0, acc1;
#pragma unroll
            for (int ks = 0; ks < 8; ++ks) {
                acc0 = __builtin_amdgcn_mfma_f32_32x32x16_bf16(
                    gf[ks], a[0][ks], ks == 0 ? z16 : acc0, 0, 0, 0);
                acc1 = __builtin_amdgcn_mfma_f32_32x32x16_bf16(
                    gf[ks], a[1][ks], ks == 0 ? z16 : acc1, 0, 0, 0);
            }
            __builtin_amdgcn_s_setprio(0);
            // in-lane reduce 16 -> 1 per m-sub (online max over qt)
            float t0 = fmaxf(acc0[0], acc0[1]);
            float t1 = fmaxf(acc1[0], acc1[1]);
#pragma unroll
            for (int j = 2; j < 16; ++j) {
                t0 = fmaxf(t0, acc0[j]);
                t1 = fmaxf(t1, acc1[j]);
            }
            if (qt == 0) { r0 = t0; r1 = t1; }
            else         { r0 = fmaxf(r0, t0); r1 = fmaxf(r1, t1); }
        }
        // fold q hi-halves, relu+eps, store
        r0 = fmaxf(r0, __shfl_xor(r0, 32));
        r1 = fmaxf(r1, __shfl_xor(r1, 32));
        const int n = bn * 8 + s;
        if (hi == 0) {
            out[(size_t)m0 * 4096 + n * 64 + h * 32 + l31]       = fmaxf(r0, 0.f) + EPS_ADD;
            out[(size_t)(m0 + 1) * 4096 + n * 64 + h * 32 + l31] = fmaxf(r1, 0.f) + EPS_ADD;
        }
    };

    // ---- step 0: drain A + stage0 (leave stage1) ----
    WAITV(4); __builtin_amdgcn_s_barrier(); SB0;
    step(0, 2); SB0;

    // ---- step 1 ----
    WAITV(6); __builtin_amdgcn_s_barrier(); SB0;
    step(1, 3); SB0;

    // ---- steps 2..5: steady WAITV(8), dist-2 prefetch ----
    WAITV(8); __builtin_amdgcn_s_barrier(); SB0;
    step(2, 4); SB0;
    WAITV(8); __builtin_amdgcn_s_barrier(); SB0;
    step(3, 5); SB0;
    WAITV(8); __builtin_amdgcn_s_barrier(); SB0;
    step(4, 6); SB0;
    WAITV(8); __builtin_amdgcn_s_barrier(); SB0;
    step(5, 7); SB0;

    // ---- step 6 (no stage issued) ----
    WAITV(8); __builtin_amdgcn_s_barrier(); SB0;
    step(6, -1); SB0;

    // ---- step 7 ----
    WAITV(4); __builtin_amdgcn_s_barrier(); SB0;
    step(7, -1);
}

// ---------------------------------------------------------------------------
extern "C" void kernel_launch(void* const* d_in, const int* in_sizes, int n_in,
                              void* d_out, int out_size, void* d_ws, size_t ws_size,
                              hipStream_t stream) {
    const float* A  = (const float*)d_in[0];
    const float* B  = (const float*)d_in[1];
    const float* Wg = (const float*)d_in[2];
    float* out = (float*)d_out;

    bf16* Afrag = (bf16*)d_ws;                                      // 512 x 8192 bf16 = 8 MiB
    bf16* Gfrag = (bf16*)((char*)d_ws + (size_t)Mdim * Pdim * Cdim * sizeof(bf16)); // 64 x 8192 bf16

    prep_kernel<<<768, 256, 0, stream>>>(A, B, Wg, Afrag, Gfrag);
    gemm_max_kernel<<<1024, 256, 0, stream>>>(Afrag, Gfrag, out);   // 8 bn x 128 mg
}

// Round 18
// 47.483 us; speedup vs baseline: 1.4696x; 1.0217x over previous
//
#include <hip/hip_runtime.h>
#include <hip/hip_bf16.h>
#include <stdint.h>

typedef __attribute__((ext_vector_type(8))) short bf16x8;
typedef __attribute__((ext_vector_type(16))) float f32x16;
using bf16 = __hip_bfloat16;

static constexpr int Mdim = 512;   // A batch
static constexpr int Ndim = 64;    // B batch
static constexpr int Cdim = 128;   // channels (K of the GEMM)
static constexpr int Pdim = 64;    // H*W positions
static constexpr float EPS_ADD = 0.001f;

#define SB0 __builtin_amdgcn_sched_barrier(0)

// ---------------------------------------------------------------------------
// async global->LDS, 16B per lane
// ---------------------------------------------------------------------------
__device__ __forceinline__ void gll16(const void* gsrc, void* ldst) {
    const __attribute__((address_space(1))) unsigned int* g =
        (const __attribute__((address_space(1))) unsigned int*)gsrc;
    __attribute__((address_space(3))) unsigned int* l =
        (__attribute__((address_space(3))) unsigned int*)(uintptr_t)ldst;
    __builtin_amdgcn_global_load_lds(g, l, 16, 0, 0);
}

// ---------------------------------------------------------------------------
// prep (fused, UNCHANGED — verified): fragment-ordered outputs.
//   A-tile (per m): idx = h*4096 + ks*512 + lane*8 + e
//     p = h*32 + (lane&31), c = ks*16 + (lane>>5)*8 + e
//   G-tile (per n): idx = qt*4096 + ks*512 + lane*8 + e
//     q = qt*32 + (lane&31), c = ks*16 + (lane>>5)*8 + e
// ---------------------------------------------------------------------------
__global__ void prep_kernel(const float* __restrict__ A, const float* __restrict__ B,
                            const float* __restrict__ Wg,
                            bf16* __restrict__ Afrag, bf16* __restrict__ Gfrag) {
    __shared__ float lds[128 * 65];
    const int t = threadIdx.x;

    if (blockIdx.x < 512) {
        const int m = blockIdx.x;
        const float* __restrict__ Am = A + (size_t)m * (Cdim * Pdim);
#pragma unroll
        for (int i = 0; i < 8; ++i) {
            int v = t + i * 256;
            int gidx = v * 4;
            int c = gidx >> 6, p = gidx & 63;
            float4 val = *reinterpret_cast<const float4*>(Am + gidx);
            float* dst = &lds[c * 65 + p];
            dst[0] = val.x; dst[1] = val.y; dst[2] = val.z; dst[3] = val.w;
        }
        __syncthreads();

        unsigned* __restrict__ dst32 = (unsigned*)(Afrag + (size_t)m * 8192);
#pragma unroll
        for (int i = 0; i < 16; ++i) {
            int pr = t + i * 256;
            int p = pr >> 6;
            int c = (pr & 63) << 1;
            float f0 = lds[c * 65 + p];
            float f1 = lds[(c + 1) * 65 + p];
            union { bf16 hh[2]; unsigned u; } pk;
            pk.hh[0] = __float2bfloat16(f0);
            pk.hh[1] = __float2bfloat16(f1);
            int h = p >> 5, l31 = p & 31;
            int ks = c >> 4, hi = (c >> 3) & 1, e = c & 7;
            dst32[h * 2048 + ks * 256 + hi * 128 + l31 * 4 + (e >> 1)] = pk.u;
        }
    } else {
        const int nb = blockIdx.x - 512;
        const int n  = nb >> 2;
        const int q0 = (nb & 3) * 16;
        const float* __restrict__ Bn = B + (size_t)n * (Cdim * Pdim);
#pragma unroll
        for (int i = 0; i < 8; ++i) {
            int v = t + i * 256;
            int gidx = v * 4;
            int c = gidx >> 6, q = gidx & 63;
            float4 val = *reinterpret_cast<const float4*>(Bn + gidx);
            float* dst = &lds[c * 65 + q];
            dst[0] = val.x; dst[1] = val.y; dst[2] = val.z; dst[3] = val.w;
        }
        __syncthreads();

        const int d  = t & 127;
        const int qb = q0 + (t >> 7) * 8;
        float acc[8] = {0.f, 0.f, 0.f, 0.f, 0.f, 0.f, 0.f, 0.f};
        for (int c = 0; c < 128; ++c) {
            float w = Wg[c * 128 + d];
#pragma unroll
            for (int qi = 0; qi < 8; ++qi)
                acc[qi] = fmaf(lds[c * 65 + qb + qi], w, acc[qi]);
        }
        bf16* __restrict__ gdst = Gfrag + (size_t)n * 8192;
        const int ks = d >> 4, hi = (d >> 3) & 1, e = d & 7;
#pragma unroll
        for (int qi = 0; qi < 8; ++qi) {
            int q = qb + qi;
            int qt = q >> 5, l31 = q & 31;
            gdst[qt * 4096 + ks * 512 + hi * 256 + l31 * 8 + e] = __float2bfloat16(acc[qi]);
        }
    }
}

// ---------------------------------------------------------------------------
// gemm_max v16: register-pipelined gf (the in-wave serial-latency fix).
// Wave = 2 m's x one p-half; a[2][8] resident. Block = 4 waves; 16 n-steps.
// Per body s: [barrier; stage(s+2); issue gfB ds-reads (buf s,qt1);
//   MFMA qt0 on gfA (preloaded); WAITV(cnt) [drains stage(s+1), provable];
//   issue gfA ds-reads for NEXT body (buf s+1,qt0) under qt1's MFMA;
//   MFMA qt1 on gfB; reduce/fold/store]. LDS-read latency never on the
//   critical path; one barrier + one counted WAITV per body.
// Ledger (5 vmcnt events/body: stage 4 + store 1; stage at top, store last):
//   body0 W(4); bodies1..13 W(5) [leave store(s-1)+stage(s+2), drain
//   through stage(s+1)]; body14 W(1) [no stage16]; body15 W(2) (no-op).
// Buffer safety: stage(s+2) writes buf (s-1)%3 after the body-s barrier,
//   which all body-(s-1) readers passed. Next-prefetch reads buf s+1 only
//   after WAITV drained stage(s+1). gfA WAR across phases is SSA-safe.
// Grid 512 = 4 bn x 128 mg -> 2 blocks/CU EXACT (no tail); (256,2), 48KB.
// bid%8 = mg%8 -> same-A blocks share an XCD L2.
// MFMA 32x32x16, mfma(G,A): D col = lane&31 = p, row = q (m74/m101).
// ---------------------------------------------------------------------------
__global__ __launch_bounds__(256, 2)
void gemm_max_kernel(const bf16* __restrict__ Afrag, const bf16* __restrict__ Gfrag,
                     float* __restrict__ out) {
    __shared__ bf16 sG[3][8192];          // 3 x 16KB rolling, fragment order
    const int tid  = threadIdx.x;
    const int lane = tid & 63;
    const int wv   = tid >> 6;            // 0..3
    const int mi = wv >> 1, h = wv & 1;   // wave: m-pair index, p-half
    const int l31 = lane & 31, hi = lane >> 5;
    const int mg = blockIdx.x & 127;      // 128 m-groups of 4
    const int bn = blockIdx.x >> 7;       // 4 n-groups of 16
    const int m0 = mg * 4 + mi * 2;       // wave handles m0, m0+1

    // ---- A resident: 16 coalesced 1KB loads (oldest vmcnt events) ----
    bf16x8 a[2][8];                       // [m-sub][ks]
#pragma unroll
    for (int u = 0; u < 2; ++u) {
        const bf16* Ap = Afrag + (size_t)(m0 + u) * 8192 + h * 4096 + lane * 8;
#pragma unroll
        for (int ks = 0; ks < 8; ++ks)
            a[u][ks] = *reinterpret_cast<const bf16x8*>(Ap + ks * 512);
    }
    asm volatile("" ::: "memory");        // pin A-loads before stage issues

    const char* Gsrc = (const char*)(Gfrag + (size_t)(bn * 16) * 8192);
    auto stageG = [&](int s) {            // 16KB: 4 x gll16 per thread
        char* dst = (char*)&sG[s % 3][0];
        const char* src = Gsrc + (size_t)s * 16384;
#pragma unroll
        for (int i = 0; i < 4; ++i) {
            int f = (i * 256 + tid) * 16;
            gll16(src + f, dst + f);
        }
    };
    stageG(0);
    stageG(1);

    const f32x16 z16 = {0.f,0.f,0.f,0.f,0.f,0.f,0.f,0.f,0.f,0.f,0.f,0.f,0.f,0.f,0.f,0.f};
    f32x16 acc0, acc1;
    bf16x8 gfA[8], gfB[8];

    auto ldgf = [&](bf16x8 (&g)[8], const char* base) {
#pragma unroll
        for (int ks = 0; ks < 8; ++ks)
            g[ks] = *reinterpret_cast<const bf16x8*>(base + ks * 1024);
    };
    auto mmcl = [&](const bf16x8 (&gf)[8]) {
        __builtin_amdgcn_s_setprio(1);
        acc0 = __builtin_amdgcn_mfma_f32_32x32x16_bf16(gf[0], a[0][0], z16, 0, 0, 0);
        acc1 = __builtin_amdgcn_mfma_f32_32x32x16_bf16(gf[0], a[1][0], z16, 0, 0, 0);
#pragma unroll
        for (int ks = 1; ks < 8; ++ks) {
            acc0 = __builtin_amdgcn_mfma_f32_32x32x16_bf16(gf[ks], a[0][ks], acc0, 0, 0, 0);
            acc1 = __builtin_amdgcn_mfma_f32_32x32x16_bf16(gf[ks], a[1][ks], acc1, 0, 0, 0);
        }
        __builtin_amdgcn_s_setprio(0);
    };
    auto red16 = [&](const f32x16& v) -> float {
        float x0 = fmaxf(v[0], v[1]),  x1 = fmaxf(v[2], v[3]);
        float x2 = fmaxf(v[4], v[5]),  x3 = fmaxf(v[6], v[7]);
        float x4 = fmaxf(v[8], v[9]),  x5 = fmaxf(v[10], v[11]);
        float x6 = fmaxf(v[12], v[13]), x7 = fmaxf(v[14], v[15]);
        x0 = fmaxf(x0, x1); x2 = fmaxf(x2, x3);
        x4 = fmaxf(x4, x5); x6 = fmaxf(x6, x7);
        return fmaxf(fmaxf(x0, x2), fmaxf(x4, x6));
    };

#define BODY(S, WV, DOSTAGE, DOPREF)                                          \
    __builtin_amdgcn_s_barrier(); SB0;                                        \
    if (DOSTAGE) stageG((S) + 2);                                             \
    ldgf(gfB, (const char*)&sG[(S) % 3][0] + 8192 + lane * 16);               \
    mmcl(gfA);                                                                \
    asm volatile("s_waitcnt vmcnt(" #WV ")" ::: "memory"); SB0;               \
    if (DOPREF) ldgf(gfA, (const char*)&sG[((S) + 1) % 3][0] + lane * 16);    \
    {                                                                         \
        float t0 = red16(acc0), t1 = red16(acc1);                             \
        mmcl(gfB);                                                            \
        t0 = fmaxf(t0, red16(acc0)); t1 = fmaxf(t1, red16(acc1));             \
        t0 = fmaxf(t0, __shfl_xor(t0, 32));                                   \
        t1 = fmaxf(t1, __shfl_xor(t1, 32));                                   \
        const int n = bn * 16 + (S);                                          \
        const float sv = hi ? t1 : t0;                                        \
        out[(size_t)(m0 + hi) * 4096 + n * 64 + h * 32 + l31] =               \
            fmaxf(sv, 0.f) + EPS_ADD;                                         \
    }

    // ---- prologue: drain stage(0) (leave stage1), preload gfA(buf0,qt0) ----
    asm volatile("s_waitcnt vmcnt(4)" ::: "memory");
    __builtin_amdgcn_s_barrier(); SB0;
    ldgf(gfA, (const char*)&sG[0][0] + lane * 16);

    BODY(0, 4, 1, 1)
    BODY(1, 5, 1, 1)
    BODY(2, 5, 1, 1)
    BODY(3, 5, 1, 1)
    BODY(4, 5, 1, 1)
    BODY(5, 5, 1, 1)
    BODY(6, 5, 1, 1)
    BODY(7, 5, 1, 1)
    BODY(8, 5, 1, 1)
    BODY(9, 5, 1, 1)
    BODY(10, 5, 1, 1)
    BODY(11, 5, 1, 1)
    BODY(12, 5, 1, 1)
    BODY(13, 5, 1, 1)
    BODY(14, 1, 0, 1)
    BODY(15, 2, 0, 0)
#undef BODY
}

// ---------------------------------------------------------------------------
extern "C" void kernel_launch(void* const* d_in, const int* in_sizes, int n_in,
                              void* d_out, int out_size, void* d_ws, size_t ws_size,
                              hipStream_t stream) {
    const float* A  = (const float*)d_in[0];
    const float* B  = (const float*)d_in[1];
    const float* Wg = (const float*)d_in[2];
    float* out = (float*)d_out;

    bf16* Afrag = (bf16*)d_ws;                                      // 512 x 8192 bf16 = 8 MiB
    bf16* Gfrag = (bf16*)((char*)d_ws + (size_t)Mdim * Pdim * Cdim * sizeof(bf16)); // 64 x 8192 bf16

    prep_kernel<<<768, 256, 0, stream>>>(A, B, Wg, Afrag, Gfrag);
    gemm_max_kernel<<<512, 256, 0, stream>>>(Afrag, Gfrag, out);   // 4 bn x 128 mg
}